// Round 4
// baseline (112.470 us; speedup 1.0000x reference)
//
#include <hip/hip_runtime.h>
#include <hip/hip_bf16.h>

typedef unsigned short u16;
typedef __attribute__((ext_vector_type(8))) short short8;
typedef __attribute__((ext_vector_type(4))) float f32x4;

#define BSZ   4096
#define INF   1024
#define FEAT  512
#define NCLS  1000
#define NPAD  1024
#define DTOT  2048

__device__ __forceinline__ u16 f2bf(float f) {
  unsigned int x = __float_as_uint(f);
  x += 0x7fffu + ((x >> 16) & 1u);   // RNE; inputs finite, no NaN path needed
  return (u16)(x >> 16);
}
__device__ __forceinline__ float bf2f(u16 h) {
  return __uint_as_float((unsigned int)h << 16);
}
__device__ __forceinline__ void gload_lds16(const void* g, void* l) {
  __builtin_amdgcn_global_load_lds(
      (const __attribute__((address_space(1))) void*)g,
      (__attribute__((address_space(3))) void*)l, 16, 0, 0);
}

// -------- fp32 -> bf16 convert, 4 source tensors in one dispatch -----------
__global__ __launch_bounds__(256) void cvt_bf16_x4(const float* __restrict__ x0,
                                                   const float* __restrict__ x1,
                                                   const float* __restrict__ x2,
                                                   const float* __restrict__ x3,
                                                   u16* __restrict__ outp, int n8) {
  int i = blockIdx.x * 256 + threadIdx.x;
  if (i >= n8) return;
  const float* in = (blockIdx.y & 2) ? ((blockIdx.y & 1) ? x3 : x2)
                                     : ((blockIdx.y & 1) ? x1 : x0);
  const float4* p = (const float4*)in;
  float4 a = p[2 * i], b = p[2 * i + 1];
  short8 o;
  o[0] = (short)f2bf(a.x); o[1] = (short)f2bf(a.y);
  o[2] = (short)f2bf(a.z); o[3] = (short)f2bf(a.w);
  o[4] = (short)f2bf(b.x); o[5] = (short)f2bf(b.y);
  o[6] = (short)f2bf(b.z); o[7] = (short)f2bf(b.w);
  *(short8*)&outp[(size_t)blockIdx.y * n8 * 8 + (size_t)i * 8] = o;
}

__global__ __launch_bounds__(256) void cvt_bf16(const float* __restrict__ in,
                                                u16* __restrict__ outp, int n8) {
  int i = blockIdx.x * 256 + threadIdx.x;
  if (i >= n8) return;
  const float4* p = (const float4*)in;
  float4 a = p[2 * i], b = p[2 * i + 1];
  short8 o;
  o[0] = (short)f2bf(a.x); o[1] = (short)f2bf(a.y);
  o[2] = (short)f2bf(a.z); o[3] = (short)f2bf(a.w);
  o[4] = (short)f2bf(b.x); o[5] = (short)f2bf(b.y);
  o[6] = (short)f2bf(b.z); o[7] = (short)f2bf(b.w);
  *(short8*)&outp[(size_t)i * 8] = o;
}

// ------------- centers: convert to bf16 (padded to 1024 rows) + c2 ---------
__global__ __launch_bounds__(256) void cvt_centers(const float* __restrict__ cen,
                                                   u16* __restrict__ Cb,
                                                   float* __restrict__ c2) {
  const int row = blockIdx.x;   // 0..1023
  const int t = threadIdx.x;    // 256 threads, 8 elems each (D=2048)
  float s = 0.f;
  if (row < NCLS) {
    const float4* p = (const float4*)(cen + (size_t)row * DTOT) + 2 * t;
    float4 a = p[0], b = p[1];
    short8 o;
    o[0] = (short)f2bf(a.x); o[1] = (short)f2bf(a.y);
    o[2] = (short)f2bf(a.z); o[3] = (short)f2bf(a.w);
    o[4] = (short)f2bf(b.x); o[5] = (short)f2bf(b.y);
    o[6] = (short)f2bf(b.z); o[7] = (short)f2bf(b.w);
    *(short8*)&Cb[(size_t)row * DTOT + t * 8] = o;
    s = a.x * a.x + a.y * a.y + a.z * a.z + a.w * a.w +
        b.x * b.x + b.y * b.y + b.z * b.z + b.w * b.w;
  } else {
    short8 z = {0, 0, 0, 0, 0, 0, 0, 0};
    *(short8*)&Cb[(size_t)row * DTOT + t * 8] = z;
  }
#pragma unroll
  for (int o = 32; o > 0; o >>= 1) s += __shfl_xor(s, o);
  __shared__ float red[4];
  if ((t & 63) == 0) red[t >> 6] = s;
  __syncthreads();
  if (t == 0) c2[row] = red[0] + red[1] + red[2] + red[3];
}

// -------------- f2[row] = sum over 64 column-half partials ------------------
__global__ __launch_bounds__(256) void reduce_f2(const float* __restrict__ f2p,
                                                 float* __restrict__ f2) {
  const int row = blockIdx.x * 256 + threadIdx.x;  // 4096
  float s = 0.f;
#pragma unroll
  for (int h = 0; h < 64; ++h) s += f2p[(size_t)h * BSZ + row];
  f2[row] = s;
}

// ---------------- feature GEMM: feat = relu(X @ W^T + b), bf16 -------------
// Tile 128x64, 4 waves (2x2), each wave 64x32. 3-buffer depth-2 pipeline:
// raw s_barrier + counted vmcnt(6) (T3/T4) -- loads get ~2 K-steps to land.
// XOR slot-swizzle (source + ds_read, LDS dest linear). XCD-chunked blockIdx.
// Epilogue fuses per-row sum-of-squares partials into f2p (deterministic).
__global__ __launch_bounds__(256) void feat_gemm(const u16* __restrict__ Xb,
                                                 const u16* __restrict__ Wb,
                                                 const float* __restrict__ bf_,
                                                 const float* __restrict__ br_,
                                                 u16* __restrict__ Fb,
                                                 float* __restrict__ f2p) {
  __shared__ u16 As[3][128 * 64];
  __shared__ u16 Bs[3][64 * 64];
  const int t = threadIdx.x;
  const int lane = t & 63;
  const int wid = t >> 6;
  const int wr = (wid >> 1) * 64;
  const int wc = (wid & 1) * 32;
  // XCD-chunked swizzle: 1024 wgs -> 128 consecutive per XCD
  const int lid = blockIdx.x;
  const int swg = (lid & 7) * 128 + (lid >> 3);
  const int m = swg >> 5;                // 0..31
  const int n = swg & 31;                // 0..31 (64-col tiles over 2048)
  const int bm0 = m * 128;
  const int g = n >> 3;                  // quadrant 0..3
  const int bn0 = (n & 7) * 64;          // col within W
  const int gc0 = n * 64;                // global feat col
  const u16* A = Xb + (size_t)g * BSZ * INF;
  const u16* Bt = Wb + (g ? (size_t)FEAT * INF : 0);
  const float* bias = g ? br_ : bf_;

  const int r8 = t >> 3;                          // staging row 0..31 (+32/it)
  const int kcs = (((t & 7) ^ (r8 & 7)) << 3);    // swizzled source slot
  const int l15 = lane & 15;
  const int l4 = lane >> 4;
  const int swz = l15 & 7;

  f32x4 acc[4][2] = {};

  auto stage = [&](int buf, int k0) {
#pragma unroll
    for (int it = 0; it < 4; ++it)
      gload_lds16(&A[(size_t)(bm0 + it * 32 + r8) * INF + k0 + kcs],
                  &As[buf][(it * 256 + (wid << 6)) * 8]);
#pragma unroll
    for (int it = 0; it < 2; ++it)
      gload_lds16(&Bt[(size_t)(bn0 + it * 32 + r8) * INF + k0 + kcs],
                  &Bs[buf][(it * 256 + (wid << 6)) * 8]);
  };
  auto comp = [&](int buf) {
#pragma unroll
    for (int ks = 0; ks < 2; ++ks) {
      const int so = (((ks * 4 + l4) ^ swz) << 3);
      short8 av[4], bv[2];
#pragma unroll
      for (int i = 0; i < 4; ++i)
        av[i] = *(const short8*)&As[buf][(wr + i * 16 + l15) * 64 + so];
#pragma unroll
      for (int j = 0; j < 2; ++j)
        bv[j] = *(const short8*)&Bs[buf][(wc + j * 16 + l15) * 64 + so];
      __builtin_amdgcn_s_setprio(1);
#pragma unroll
      for (int i = 0; i < 4; ++i)
#pragma unroll
        for (int j = 0; j < 2; ++j)
          acc[i][j] = __builtin_amdgcn_mfma_f32_16x16x32_bf16(av[i], bv[j],
                                                              acc[i][j], 0, 0, 0);
      __builtin_amdgcn_s_setprio(0);
    }
  };

  const int NT = INF / 64;   // 16
  int ba = 0, bb = 1, bc = 2;
  stage(0, 0);
  stage(1, 64);
  for (int tt = 0; tt < NT; ++tt) {
    if (tt < NT - 1)
      asm volatile("s_waitcnt vmcnt(6) lgkmcnt(0)" ::: "memory");
    else
      asm volatile("s_waitcnt vmcnt(0) lgkmcnt(0)" ::: "memory");
    __builtin_amdgcn_s_barrier();
    if (tt + 2 < NT) stage(bc, (tt + 2) * 64);
    comp(ba);
    int tmp = ba; ba = bb; bb = bc; bc = tmp;
  }

  // epilogue: bias + relu + bf16 store + per-row sumsq partial
  const float bval0 = bias[bn0 + wc + l15];
  const float bval1 = bias[bn0 + wc + 16 + l15];
  const int hidx = n * 2 + (wid & 1);
#pragma unroll
  for (int i = 0; i < 4; ++i) {
#pragma unroll
    for (int r = 0; r < 4; ++r) {
      const int row = bm0 + wr + i * 16 + l4 * 4 + r;
      float v0 = fmaxf(acc[i][0][r] + bval0, 0.f);
      float v1 = fmaxf(acc[i][1][r] + bval1, 0.f);
      u16 h0 = f2bf(v0), h1 = f2bf(v1);
      Fb[(size_t)row * DTOT + gc0 + wc + l15] = h0;
      Fb[(size_t)row * DTOT + gc0 + wc + 16 + l15] = h1;
      float a0 = bf2f(h0), a1 = bf2f(h1);
      float s = a0 * a0 + a1 * a1;
      s += __shfl_xor(s, 1);
      s += __shfl_xor(s, 2);
      s += __shfl_xor(s, 4);
      s += __shfl_xor(s, 8);
      if (l15 == 0) f2p[(size_t)hidx * BSZ + row] = s;
    }
  }
}

// ------- distance GEMM: out = -0.1*sqrt(max(f2 + c2 - 2*feat.c, 0)) --------
// Same 128x64 / 3-buffer / counted-vmcnt structure. grid 512 = 2 blocks/CU.
__global__ __launch_bounds__(256) void dist_gemm(const u16* __restrict__ Fb,
                                                 const u16* __restrict__ Cb,
                                                 const float* __restrict__ f2,
                                                 const float* __restrict__ c2,
                                                 float* __restrict__ out) {
  __shared__ u16 As[3][128 * 64];
  __shared__ u16 Bs[3][64 * 64];
  const int t = threadIdx.x;
  const int lane = t & 63;
  const int wid = t >> 6;
  const int wr = (wid >> 1) * 64;
  const int wc = (wid & 1) * 32;
  const int lid = blockIdx.x;
  const int swg = (lid & 7) * 64 + (lid >> 3);
  const int bm0 = (swg >> 4) * 128;
  const int bn0 = (swg & 15) * 64;       // padded class col

  const int r8 = t >> 3;
  const int kcs = (((t & 7) ^ (r8 & 7)) << 3);
  const int l15 = lane & 15;
  const int l4 = lane >> 4;
  const int swz = l15 & 7;

  f32x4 acc[4][2] = {};

  auto stage = [&](int buf, int k0) {
#pragma unroll
    for (int it = 0; it < 4; ++it)
      gload_lds16(&Fb[(size_t)(bm0 + it * 32 + r8) * DTOT + k0 + kcs],
                  &As[buf][(it * 256 + (wid << 6)) * 8]);
#pragma unroll
    for (int it = 0; it < 2; ++it)
      gload_lds16(&Cb[(size_t)(bn0 + it * 32 + r8) * DTOT + k0 + kcs],
                  &Bs[buf][(it * 256 + (wid << 6)) * 8]);
  };
  auto comp = [&](int buf) {
#pragma unroll
    for (int ks = 0; ks < 2; ++ks) {
      const int so = (((ks * 4 + l4) ^ swz) << 3);
      short8 av[4], bv[2];
#pragma unroll
      for (int i = 0; i < 4; ++i)
        av[i] = *(const short8*)&As[buf][(wr + i * 16 + l15) * 64 + so];
#pragma unroll
      for (int j = 0; j < 2; ++j)
        bv[j] = *(const short8*)&Bs[buf][(wc + j * 16 + l15) * 64 + so];
      __builtin_amdgcn_s_setprio(1);
#pragma unroll
      for (int i = 0; i < 4; ++i)
#pragma unroll
        for (int j = 0; j < 2; ++j)
          acc[i][j] = __builtin_amdgcn_mfma_f32_16x16x32_bf16(av[i], bv[j],
                                                              acc[i][j], 0, 0, 0);
      __builtin_amdgcn_s_setprio(0);
    }
  };

  const int NT = DTOT / 64;  // 32
  int ba = 0, bb = 1, bc = 2;
  stage(0, 0);
  stage(1, 64);
  for (int tt = 0; tt < NT; ++tt) {
    if (tt < NT - 1)
      asm volatile("s_waitcnt vmcnt(6) lgkmcnt(0)" ::: "memory");
    else
      asm volatile("s_waitcnt vmcnt(0) lgkmcnt(0)" ::: "memory");
    __builtin_amdgcn_s_barrier();
    if (tt + 2 < NT) stage(bc, (tt + 2) * 64);
    comp(ba);
    int tmp = ba; ba = bb; bb = bc; bc = tmp;
  }

  const int col0 = bn0 + wc + l15;
  const int col1 = col0 + 16;
  const float c2v0 = c2[col0];
  const float c2v1 = c2[col1];
#pragma unroll
  for (int i = 0; i < 4; ++i) {
#pragma unroll
    for (int r = 0; r < 4; ++r) {
      const int row = bm0 + wr + i * 16 + l4 * 4 + r;
      const float f2v = f2[row];
      float d0 = f2v + c2v0 - 2.f * acc[i][0][r];
      float d1 = f2v + c2v1 - 2.f * acc[i][1][r];
      float v0 = -0.1f * sqrtf(fmaxf(d0, 0.f));
      float v1 = -0.1f * sqrtf(fmaxf(d1, 0.f));
      if (col0 < NCLS) out[(size_t)row * NCLS + col0] = v0;
      if (col1 < NCLS) out[(size_t)row * NCLS + col1] = v1;
    }
  }
}

extern "C" void kernel_launch(void* const* d_in, const int* in_sizes, int n_in,
                              void* d_out, int out_size, void* d_ws, size_t ws_size,
                              hipStream_t stream) {
  const float* x    = (const float*)d_in[0];
  const float* x90  = (const float*)d_in[1];
  const float* x180 = (const float*)d_in[2];
  const float* x270 = (const float*)d_in[3];
  const float* W_f  = (const float*)d_in[4];
  const float* b_f  = (const float*)d_in[5];
  const float* W_r  = (const float*)d_in[6];
  const float* b_r  = (const float*)d_in[7];
  const float* cen  = (const float*)d_in[8];
  float* out = (float*)d_out;

  // workspace layout (bf16 as u16)
  u16* Xb = (u16*)d_ws;                         // [4][4096][1024]
  u16* Wb = Xb + 4ull * BSZ * INF;              // [2][512][1024]
  u16* Cb = Wb + 2ull * FEAT * INF;             // [1024][2048]
  u16* Fb = Cb + (size_t)NPAD * DTOT;           // [4096][2048]
  float* f2 = (float*)(Fb + (size_t)BSZ * DTOT);// [4096]
  float* c2 = f2 + BSZ;                         // [1024]
  float* f2p = c2 + NPAD;                       // [64][4096]

  const int n8x = BSZ * INF / 8;   // 524288
  const int n8w = FEAT * INF / 8;  // 65536
  cvt_bf16_x4<<<dim3((n8x + 255) / 256, 4), 256, 0, stream>>>(x, x90, x180, x270,
                                                              Xb, n8x);
  cvt_bf16<<<(n8w + 255) / 256, 256, 0, stream>>>(W_f, Wb, n8w);
  cvt_bf16<<<(n8w + 255) / 256, 256, 0, stream>>>(W_r, Wb + (size_t)FEAT * INF, n8w);
  cvt_centers<<<NPAD, 256, 0, stream>>>(cen, Cb, c2);

  feat_gemm<<<1024, 256, 0, stream>>>(Xb, Wb, b_f, b_r, Fb, f2p);
  reduce_f2<<<BSZ / 256, 256, 0, stream>>>(f2p, f2);
  dist_gemm<<<512, 256, 0, stream>>>(Fb, Cb, f2, c2, out);
}

// Round 5
// 103.866 us; speedup vs baseline: 1.0828x; 1.0828x over previous
//
#include <hip/hip_runtime.h>
#include <hip/hip_bf16.h>

typedef unsigned short u16;
typedef __attribute__((ext_vector_type(8))) short short8;
typedef __attribute__((ext_vector_type(4))) float f32x4;

#define BSZ   4096
#define INF   1024
#define FEAT  512
#define NCLS  1000
#define NPAD  1024
#define DTOT  2048

__device__ __forceinline__ u16 f2bf(float f) {
  unsigned int x = __float_as_uint(f);
  x += 0x7fffu + ((x >> 16) & 1u);   // RNE; inputs finite, no NaN path needed
  return (u16)(x >> 16);
}
__device__ __forceinline__ float bf2f(u16 h) {
  return __uint_as_float((unsigned int)h << 16);
}
__device__ __forceinline__ void gload_lds16(const void* g, void* l) {
  __builtin_amdgcn_global_load_lds(
      (const __attribute__((address_space(1))) void*)g,
      (__attribute__((address_space(3))) void*)l, 16, 0, 0);
}

// -------- fp32 -> bf16 convert, 4 source tensors in one dispatch -----------
__global__ __launch_bounds__(256) void cvt_bf16_x4(const float* __restrict__ x0,
                                                   const float* __restrict__ x1,
                                                   const float* __restrict__ x2,
                                                   const float* __restrict__ x3,
                                                   u16* __restrict__ outp, int n8) {
  int i = blockIdx.x * 256 + threadIdx.x;
  if (i >= n8) return;
  const float* in = (blockIdx.y & 2) ? ((blockIdx.y & 1) ? x3 : x2)
                                     : ((blockIdx.y & 1) ? x1 : x0);
  const float4* p = (const float4*)in;
  float4 a = p[2 * i], b = p[2 * i + 1];
  short8 o;
  o[0] = (short)f2bf(a.x); o[1] = (short)f2bf(a.y);
  o[2] = (short)f2bf(a.z); o[3] = (short)f2bf(a.w);
  o[4] = (short)f2bf(b.x); o[5] = (short)f2bf(b.y);
  o[6] = (short)f2bf(b.z); o[7] = (short)f2bf(b.w);
  *(short8*)&outp[(size_t)blockIdx.y * n8 * 8 + (size_t)i * 8] = o;
}

__global__ __launch_bounds__(256) void cvt_bf16(const float* __restrict__ in,
                                                u16* __restrict__ outp, int n8) {
  int i = blockIdx.x * 256 + threadIdx.x;
  if (i >= n8) return;
  const float4* p = (const float4*)in;
  float4 a = p[2 * i], b = p[2 * i + 1];
  short8 o;
  o[0] = (short)f2bf(a.x); o[1] = (short)f2bf(a.y);
  o[2] = (short)f2bf(a.z); o[3] = (short)f2bf(a.w);
  o[4] = (short)f2bf(b.x); o[5] = (short)f2bf(b.y);
  o[6] = (short)f2bf(b.z); o[7] = (short)f2bf(b.w);
  *(short8*)&outp[(size_t)i * 8] = o;
}

// ------------- centers: convert to bf16 (padded to 1024 rows) + c2 ---------
__global__ __launch_bounds__(256) void cvt_centers(const float* __restrict__ cen,
                                                   u16* __restrict__ Cb,
                                                   float* __restrict__ c2) {
  const int row = blockIdx.x;   // 0..1023
  const int t = threadIdx.x;    // 256 threads, 8 elems each (D=2048)
  float s = 0.f;
  if (row < NCLS) {
    const float4* p = (const float4*)(cen + (size_t)row * DTOT) + 2 * t;
    float4 a = p[0], b = p[1];
    short8 o;
    o[0] = (short)f2bf(a.x); o[1] = (short)f2bf(a.y);
    o[2] = (short)f2bf(a.z); o[3] = (short)f2bf(a.w);
    o[4] = (short)f2bf(b.x); o[5] = (short)f2bf(b.y);
    o[6] = (short)f2bf(b.z); o[7] = (short)f2bf(b.w);
    *(short8*)&Cb[(size_t)row * DTOT + t * 8] = o;
    s = a.x * a.x + a.y * a.y + a.z * a.z + a.w * a.w +
        b.x * b.x + b.y * b.y + b.z * b.z + b.w * b.w;
  } else {
    short8 z = {0, 0, 0, 0, 0, 0, 0, 0};
    *(short8*)&Cb[(size_t)row * DTOT + t * 8] = z;
  }
#pragma unroll
  for (int o = 32; o > 0; o >>= 1) s += __shfl_xor(s, o);
  __shared__ float red[4];
  if ((t & 63) == 0) red[t >> 6] = s;
  __syncthreads();
  if (t == 0) c2[row] = red[0] + red[1] + red[2] + red[3];
}

// -------------- f2[row] = sum over 64 column-half partials ------------------
__global__ __launch_bounds__(256) void reduce_f2(const float* __restrict__ f2p,
                                                 float* __restrict__ f2) {
  const int row = blockIdx.x * 256 + threadIdx.x;  // 4096
  float s = 0.f;
#pragma unroll
  for (int h = 0; h < 64; ++h) s += f2p[(size_t)h * BSZ + row];
  f2[row] = s;
}

// ---------------- feature GEMM: feat = relu(X @ W^T + b), bf16 -------------
// Tile 64x64, 4 waves (2x2, wave tile 32x32), single-buffer 16 KB LDS, m97
// 2-barrier loop. Grid 2048 blocks = 8/CU (occupancy is the lever: dist wall
// was invariant across 3 inner-loop schedules at 2 blocks/CU). XOR
// slot-swizzle on global source + ds_read (LDS dest linear). XCD-chunked.
// Epilogue fuses bias+relu+store and per-row sumsq partials (f2p).
__global__ __launch_bounds__(256) void feat_gemm(const u16* __restrict__ Xb,
                                                 const u16* __restrict__ Wb,
                                                 const float* __restrict__ bf_,
                                                 const float* __restrict__ br_,
                                                 u16* __restrict__ Fb,
                                                 float* __restrict__ f2p) {
  __shared__ u16 As[64 * 64];
  __shared__ u16 Bs[64 * 64];
  const int t = threadIdx.x;
  const int lane = t & 63;
  const int wid = t >> 6;
  const int wr = (wid >> 1) * 32;
  const int wc = (wid & 1) * 32;
  // XCD-chunked swizzle: 2048 wgs -> 256 consecutive per XCD
  const int lid = blockIdx.x;
  const int swg = (lid & 7) * 256 + (lid >> 3);
  const int m = swg >> 5;                // 0..63 (64-row tiles)
  const int n = swg & 31;                // 0..31 (64-col tiles over 2048)
  const int bm0 = m * 64;
  const int g = n >> 3;                  // quadrant 0..3
  const int bn0 = (n & 7) * 64;          // col within W
  const int gc0 = n * 64;                // global feat col
  const u16* A = Xb + (size_t)g * BSZ * INF;
  const u16* Bt = Wb + (g ? (size_t)FEAT * INF : 0);
  const float* bias = g ? br_ : bf_;

  const int r8 = t >> 3;                          // staging row 0..31 (+32/it)
  const int kcs = (((t & 7) ^ (r8 & 7)) << 3);    // swizzled source slot
  const int l15 = lane & 15;
  const int l4 = lane >> 4;
  const int swz = l15 & 7;

  f32x4 acc[2][2] = {};

  for (int k0 = 0; k0 < INF; k0 += 64) {
    __syncthreads();
#pragma unroll
    for (int it = 0; it < 2; ++it) {
      gload_lds16(&A[(size_t)(bm0 + it * 32 + r8) * INF + k0 + kcs],
                  &As[(it * 256 + (wid << 6)) * 8]);
      gload_lds16(&Bt[(size_t)(bn0 + it * 32 + r8) * INF + k0 + kcs],
                  &Bs[(it * 256 + (wid << 6)) * 8]);
    }
    __syncthreads();
#pragma unroll
    for (int ks = 0; ks < 2; ++ks) {
      const int so = (((ks * 4 + l4) ^ swz) << 3);
      short8 av[2], bv[2];
#pragma unroll
      for (int i = 0; i < 2; ++i)
        av[i] = *(const short8*)&As[(wr + i * 16 + l15) * 64 + so];
#pragma unroll
      for (int j = 0; j < 2; ++j)
        bv[j] = *(const short8*)&Bs[(wc + j * 16 + l15) * 64 + so];
#pragma unroll
      for (int i = 0; i < 2; ++i)
#pragma unroll
        for (int j = 0; j < 2; ++j)
          acc[i][j] = __builtin_amdgcn_mfma_f32_16x16x32_bf16(av[i], bv[j],
                                                              acc[i][j], 0, 0, 0);
    }
  }

  // epilogue: bias + relu + bf16 store + per-row sumsq partial
  const float bval0 = bias[bn0 + wc + l15];
  const float bval1 = bias[bn0 + wc + 16 + l15];
  const int hidx = n * 2 + (wid & 1);    // 32-col half index 0..63
#pragma unroll
  for (int i = 0; i < 2; ++i) {
#pragma unroll
    for (int r = 0; r < 4; ++r) {
      const int row = bm0 + wr + i * 16 + l4 * 4 + r;
      float v0 = fmaxf(acc[i][0][r] + bval0, 0.f);
      float v1 = fmaxf(acc[i][1][r] + bval1, 0.f);
      u16 h0 = f2bf(v0), h1 = f2bf(v1);
      Fb[(size_t)row * DTOT + gc0 + wc + l15] = h0;
      Fb[(size_t)row * DTOT + gc0 + wc + 16 + l15] = h1;
      float a0 = bf2f(h0), a1 = bf2f(h1);
      float s = a0 * a0 + a1 * a1;
      s += __shfl_xor(s, 1);
      s += __shfl_xor(s, 2);
      s += __shfl_xor(s, 4);
      s += __shfl_xor(s, 8);
      if (l15 == 0) f2p[(size_t)hidx * BSZ + row] = s;
    }
  }
}

// ------- distance GEMM: out = -0.1*sqrt(max(f2 + c2 - 2*feat.c, 0)) --------
// Same 64x64 single-buffer structure. Grid 1024 = 4 blocks/CU, 16 waves/CU.
__global__ __launch_bounds__(256) void dist_gemm(const u16* __restrict__ Fb,
                                                 const u16* __restrict__ Cb,
                                                 const float* __restrict__ f2,
                                                 const float* __restrict__ c2,
                                                 float* __restrict__ out) {
  __shared__ u16 As[64 * 64];
  __shared__ u16 Bs[64 * 64];
  const int t = threadIdx.x;
  const int lane = t & 63;
  const int wid = t >> 6;
  const int wr = (wid >> 1) * 32;
  const int wc = (wid & 1) * 32;
  // XCD-chunked: 1024 wgs -> 128 consecutive per XCD; m-chunk matches feat's
  // writer XCD so the Fb A-panel is local-L2 warm.
  const int lid = blockIdx.x;
  const int swg = (lid & 7) * 128 + (lid >> 3);
  const int m = swg >> 4;                // 0..63
  const int n = swg & 15;                // 0..15
  const int bm0 = m * 64;
  const int bn0 = n * 64;                // padded class col

  const int r8 = t >> 3;
  const int kcs = (((t & 7) ^ (r8 & 7)) << 3);
  const int l15 = lane & 15;
  const int l4 = lane >> 4;
  const int swz = l15 & 7;

  f32x4 acc[2][2] = {};

  for (int k0 = 0; k0 < DTOT; k0 += 64) {
    __syncthreads();
#pragma unroll
    for (int it = 0; it < 2; ++it) {
      gload_lds16(&Fb[(size_t)(bm0 + it * 32 + r8) * DTOT + k0 + kcs],
                  &As[(it * 256 + (wid << 6)) * 8]);
      gload_lds16(&Cb[(size_t)(bn0 + it * 32 + r8) * DTOT + k0 + kcs],
                  &Bs[(it * 256 + (wid << 6)) * 8]);
    }
    __syncthreads();
#pragma unroll
    for (int ks = 0; ks < 2; ++ks) {
      const int so = (((ks * 4 + l4) ^ swz) << 3);
      short8 av[2], bv[2];
#pragma unroll
      for (int i = 0; i < 2; ++i)
        av[i] = *(const short8*)&As[(wr + i * 16 + l15) * 64 + so];
#pragma unroll
      for (int j = 0; j < 2; ++j)
        bv[j] = *(const short8*)&Bs[(wc + j * 16 + l15) * 64 + so];
#pragma unroll
      for (int i = 0; i < 2; ++i)
#pragma unroll
        for (int j = 0; j < 2; ++j)
          acc[i][j] = __builtin_amdgcn_mfma_f32_16x16x32_bf16(av[i], bv[j],
                                                              acc[i][j], 0, 0, 0);
    }
  }

  const int col0 = bn0 + wc + l15;
  const int col1 = col0 + 16;
  const float c2v0 = c2[col0];
  const float c2v1 = c2[col1];
#pragma unroll
  for (int i = 0; i < 2; ++i) {
#pragma unroll
    for (int r = 0; r < 4; ++r) {
      const int row = bm0 + wr + i * 16 + l4 * 4 + r;
      const float f2v = f2[row];
      float d0 = f2v + c2v0 - 2.f * acc[i][0][r];
      float d1 = f2v + c2v1 - 2.f * acc[i][1][r];
      float v0 = -0.1f * sqrtf(fmaxf(d0, 0.f));
      float v1 = -0.1f * sqrtf(fmaxf(d1, 0.f));
      if (col0 < NCLS) out[(size_t)row * NCLS + col0] = v0;
      if (col1 < NCLS) out[(size_t)row * NCLS + col1] = v1;
    }
  }
}

extern "C" void kernel_launch(void* const* d_in, const int* in_sizes, int n_in,
                              void* d_out, int out_size, void* d_ws, size_t ws_size,
                              hipStream_t stream) {
  const float* x    = (const float*)d_in[0];
  const float* x90  = (const float*)d_in[1];
  const float* x180 = (const float*)d_in[2];
  const float* x270 = (const float*)d_in[3];
  const float* W_f  = (const float*)d_in[4];
  const float* b_f  = (const float*)d_in[5];
  const float* W_r  = (const float*)d_in[6];
  const float* b_r  = (const float*)d_in[7];
  const float* cen  = (const float*)d_in[8];
  float* out = (float*)d_out;

  // workspace layout (bf16 as u16)
  u16* Xb = (u16*)d_ws;                         // [4][4096][1024]
  u16* Wb = Xb + 4ull * BSZ * INF;              // [2][512][1024]
  u16* Cb = Wb + 2ull * FEAT * INF;             // [1024][2048]
  u16* Fb = Cb + (size_t)NPAD * DTOT;           // [4096][2048]
  float* f2 = (float*)(Fb + (size_t)BSZ * DTOT);// [4096]
  float* c2 = f2 + BSZ;                         // [1024]
  float* f2p = c2 + NPAD;                       // [64][4096]

  const int n8x = BSZ * INF / 8;   // 524288
  const int n8w = FEAT * INF / 8;  // 65536
  cvt_bf16_x4<<<dim3((n8x + 255) / 256, 4), 256, 0, stream>>>(x, x90, x180, x270,
                                                              Xb, n8x);
  cvt_bf16<<<(n8w + 255) / 256, 256, 0, stream>>>(W_f, Wb, n8w);
  cvt_bf16<<<(n8w + 255) / 256, 256, 0, stream>>>(W_r, Wb + (size_t)FEAT * INF, n8w);
  cvt_centers<<<NPAD, 256, 0, stream>>>(cen, Cb, c2);

  feat_gemm<<<2048, 256, 0, stream>>>(Xb, Wb, b_f, b_r, Fb, f2p);
  reduce_f2<<<BSZ / 256, 256, 0, stream>>>(f2p, f2);
  dist_gemm<<<1024, 256, 0, stream>>>(Fb, Cb, f2, c2, out);
}

// Round 6
// 87.764 us; speedup vs baseline: 1.2815x; 1.1835x over previous
//
#include <hip/hip_runtime.h>
#include <hip/hip_bf16.h>

typedef unsigned short u16;
typedef __attribute__((ext_vector_type(8))) short short8;
typedef __attribute__((ext_vector_type(4))) float f32x4;

#define BSZ   4096
#define INF   1024
#define FEAT  512
#define NCLS  1000
#define NPAD  1024
#define DTOT  2048

__device__ __forceinline__ u16 f2bf(float f) {
  unsigned int x = __float_as_uint(f);
  x += 0x7fffu + ((x >> 16) & 1u);   // RNE; inputs finite, no NaN path needed
  return (u16)(x >> 16);
}
__device__ __forceinline__ float bf2f(u16 h) {
  return __uint_as_float((unsigned int)h << 16);
}
__device__ __forceinline__ void gload_lds16(const void* g, void* l) {
  __builtin_amdgcn_global_load_lds(
      (const __attribute__((address_space(1))) void*)g,
      (__attribute__((address_space(3))) void*)l, 16, 0, 0);
}

// -------- fp32 -> bf16 convert, 4 source tensors in one dispatch -----------
__global__ __launch_bounds__(256) void cvt_bf16_x4(const float* __restrict__ x0,
                                                   const float* __restrict__ x1,
                                                   const float* __restrict__ x2,
                                                   const float* __restrict__ x3,
                                                   u16* __restrict__ outp, int n8) {
  int i = blockIdx.x * 256 + threadIdx.x;
  if (i >= n8) return;
  const float* in = (blockIdx.y & 2) ? ((blockIdx.y & 1) ? x3 : x2)
                                     : ((blockIdx.y & 1) ? x1 : x0);
  const float4* p = (const float4*)in;
  float4 a = p[2 * i], b = p[2 * i + 1];
  short8 o;
  o[0] = (short)f2bf(a.x); o[1] = (short)f2bf(a.y);
  o[2] = (short)f2bf(a.z); o[3] = (short)f2bf(a.w);
  o[4] = (short)f2bf(b.x); o[5] = (short)f2bf(b.y);
  o[6] = (short)f2bf(b.z); o[7] = (short)f2bf(b.w);
  *(short8*)&outp[(size_t)blockIdx.y * n8 * 8 + (size_t)i * 8] = o;
}

__global__ __launch_bounds__(256) void cvt_bf16(const float* __restrict__ in,
                                                u16* __restrict__ outp, int n8) {
  int i = blockIdx.x * 256 + threadIdx.x;
  if (i >= n8) return;
  const float4* p = (const float4*)in;
  float4 a = p[2 * i], b = p[2 * i + 1];
  short8 o;
  o[0] = (short)f2bf(a.x); o[1] = (short)f2bf(a.y);
  o[2] = (short)f2bf(a.z); o[3] = (short)f2bf(a.w);
  o[4] = (short)f2bf(b.x); o[5] = (short)f2bf(b.y);
  o[6] = (short)f2bf(b.z); o[7] = (short)f2bf(b.w);
  *(short8*)&outp[(size_t)i * 8] = o;
}

// ------------- centers: convert to bf16 (padded to 1024 rows) + c2 ---------
__global__ __launch_bounds__(256) void cvt_centers(const float* __restrict__ cen,
                                                   u16* __restrict__ Cb,
                                                   float* __restrict__ c2) {
  const int row = blockIdx.x;   // 0..1023
  const int t = threadIdx.x;    // 256 threads, 8 elems each (D=2048)
  float s = 0.f;
  if (row < NCLS) {
    const float4* p = (const float4*)(cen + (size_t)row * DTOT) + 2 * t;
    float4 a = p[0], b = p[1];
    short8 o;
    o[0] = (short)f2bf(a.x); o[1] = (short)f2bf(a.y);
    o[2] = (short)f2bf(a.z); o[3] = (short)f2bf(a.w);
    o[4] = (short)f2bf(b.x); o[5] = (short)f2bf(b.y);
    o[6] = (short)f2bf(b.z); o[7] = (short)f2bf(b.w);
    *(short8*)&Cb[(size_t)row * DTOT + t * 8] = o;
    s = a.x * a.x + a.y * a.y + a.z * a.z + a.w * a.w +
        b.x * b.x + b.y * b.y + b.z * b.z + b.w * b.w;
  } else {
    short8 z = {0, 0, 0, 0, 0, 0, 0, 0};
    *(short8*)&Cb[(size_t)row * DTOT + t * 8] = z;
  }
#pragma unroll
  for (int o = 32; o > 0; o >>= 1) s += __shfl_xor(s, o);
  __shared__ float red[4];
  if ((t & 63) == 0) red[t >> 6] = s;
  __syncthreads();
  if (t == 0) c2[row] = red[0] + red[1] + red[2] + red[3];
}

// -------------- f2[row] = sum over 32 column-half partials ------------------
__global__ __launch_bounds__(256) void reduce_f2(const float* __restrict__ f2p,
                                                 float* __restrict__ f2) {
  const int row = blockIdx.x * 256 + threadIdx.x;  // 4096
  float s = 0.f;
#pragma unroll
  for (int h = 0; h < 32; ++h) s += f2p[(size_t)h * BSZ + row];
  f2[row] = s;
}

// ---------------- feature GEMM: feat = relu(X @ W^T + b), bf16 -------------
// R3's best-measured config: 128x128 tile, 4 waves (2x2, wave 64x64), dbuf
// 2-barrier loop, XOR slot-swizzle, XCD-chunked. Grid 512 = 2 blocks/CU
// (~860 TF measured). Epilogue fuses bias+relu+store+f2 partials.
__global__ __launch_bounds__(256) void feat_gemm(const u16* __restrict__ Xb,
                                                 const u16* __restrict__ Wb,
                                                 const float* __restrict__ bf_,
                                                 const float* __restrict__ br_,
                                                 u16* __restrict__ Fb,
                                                 float* __restrict__ f2p) {
  __shared__ u16 As[2][128 * 64];
  __shared__ u16 Bs[2][128 * 64];
  const int t = threadIdx.x;
  const int lane = t & 63;
  const int wid = t >> 6;
  const int wr = (wid >> 1) * 64;
  const int wc = (wid & 1) * 64;
  // XCD-chunked swizzle: 512 wgs -> 64 consecutive per XCD
  const int lid = blockIdx.x;
  const int swg = (lid & 7) * 64 + (lid >> 3);
  const int bm0 = (swg >> 4) * 128;      // M block
  const int n  = swg & 15;               // N block 0..15
  const int gc0 = n * 128;               // global feat col
  const int g = n >> 2;                  // quadrant 0..3
  const int bn0 = (n & 3) * 128;         // col within W
  const u16* A = Xb + (size_t)g * BSZ * INF;
  const u16* Bt = Wb + (g ? (size_t)FEAT * INF : 0);
  const float* bias = g ? br_ : bf_;

  const int r8 = t >> 3;                          // staging row 0..31 (+32/it)
  const int kcs = (((t & 7) ^ (r8 & 7)) << 3);    // swizzled source slot
  const int l15 = lane & 15;
  const int l4 = lane >> 4;
  const int swz = l15 & 7;

  f32x4 acc[4][4] = {};

  auto stage = [&](int buf, int k0) {
#pragma unroll
    for (int it = 0; it < 4; ++it) {
      gload_lds16(&A[(size_t)(bm0 + it * 32 + r8) * INF + k0 + kcs],
                  &As[buf][(it * 256 + (wid << 6)) * 8]);
      gload_lds16(&Bt[(size_t)(bn0 + it * 32 + r8) * INF + k0 + kcs],
                  &Bs[buf][(it * 256 + (wid << 6)) * 8]);
    }
  };
  auto comp = [&](int buf) {
#pragma unroll
    for (int ks = 0; ks < 2; ++ks) {
      const int so = (((ks * 4 + l4) ^ swz) << 3);
      short8 av[4], bv[4];
#pragma unroll
      for (int i = 0; i < 4; ++i)
        av[i] = *(const short8*)&As[buf][(wr + i * 16 + l15) * 64 + so];
#pragma unroll
      for (int j = 0; j < 4; ++j)
        bv[j] = *(const short8*)&Bs[buf][(wc + j * 16 + l15) * 64 + so];
#pragma unroll
      for (int i = 0; i < 4; ++i)
#pragma unroll
        for (int j = 0; j < 4; ++j)
          acc[i][j] = __builtin_amdgcn_mfma_f32_16x16x32_bf16(av[i], bv[j],
                                                              acc[i][j], 0, 0, 0);
    }
  };

  stage(0, 0);
  __syncthreads();
  for (int k0 = 0; k0 < INF; k0 += 128) {
    stage(1, k0 + 64);
    comp(0);
    __syncthreads();
    if (k0 + 128 < INF) stage(0, k0 + 128);
    comp(1);
    __syncthreads();
  }

  // epilogue: bias + relu + bf16 store + per-row sumsq partial (64-col half)
  float bval[4];
#pragma unroll
  for (int j = 0; j < 4; ++j) bval[j] = bias[bn0 + wc + j * 16 + l15];
  const int hidx = n * 2 + (wid & 1);    // 64-col half index 0..31
#pragma unroll
  for (int i = 0; i < 4; ++i) {
#pragma unroll
    for (int r = 0; r < 4; ++r) {
      const int row = bm0 + wr + i * 16 + l4 * 4 + r;
      float s = 0.f;
#pragma unroll
      for (int j = 0; j < 4; ++j) {
        float v = fmaxf(acc[i][j][r] + bval[j], 0.f);
        u16 h = f2bf(v);
        Fb[(size_t)row * DTOT + gc0 + wc + j * 16 + l15] = h;
        float a0 = bf2f(h);
        s += a0 * a0;
      }
      s += __shfl_xor(s, 1);
      s += __shfl_xor(s, 2);
      s += __shfl_xor(s, 4);
      s += __shfl_xor(s, 8);
      if (l15 == 0) f2p[(size_t)hidx * BSZ + row] = s;
    }
  }
}

// ---- distance GEMM split-K: P[k] = feat[:, k*1024:(k+1)*1024] @ Cb^T ------
// 128x128 tile, dbuf, grid 32m x 8n x 2k = 512 blocks = 2/CU -- identical
// loop shape to feat_gemm (16 K-steps), which measured ~860 TF.
__global__ __launch_bounds__(256) void dist_gemm_sk(const u16* __restrict__ Fb,
                                                    const u16* __restrict__ Cb,
                                                    float* __restrict__ P) {
  __shared__ u16 As[2][128 * 64];
  __shared__ u16 Bs[2][128 * 64];
  const int t = threadIdx.x;
  const int lane = t & 63;
  const int wid = t >> 6;
  const int wr = (wid >> 1) * 64;
  const int wc = (wid & 1) * 64;
  // XCD-chunked: 512 wgs -> 64 consecutive per XCD; each XCD owns 4 m-panels
  // (both k-splits + all 8 n-tiles -> Cb (4MB) L2-resident, Fb panel reused).
  const int lid = blockIdx.x;
  const int swg = (lid & 7) * 64 + (lid >> 3);
  const int n = swg & 7;                 // 0..7
  const int kidx = (swg >> 3) & 1;       // K split 0..1
  const int bm0 = (swg >> 4) * 128;      // 0..31 -> rows
  const int bn0 = n * 128;               // padded class col
  const int kbase = kidx * 1024;

  const int r8 = t >> 3;
  const int kcs = (((t & 7) ^ (r8 & 7)) << 3);
  const int l15 = lane & 15;
  const int l4 = lane >> 4;
  const int swz = l15 & 7;

  f32x4 acc[4][4] = {};

  auto stage = [&](int buf, int k0) {
#pragma unroll
    for (int it = 0; it < 4; ++it) {
      gload_lds16(&Fb[(size_t)(bm0 + it * 32 + r8) * DTOT + k0 + kcs],
                  &As[buf][(it * 256 + (wid << 6)) * 8]);
      gload_lds16(&Cb[(size_t)(bn0 + it * 32 + r8) * DTOT + k0 + kcs],
                  &Bs[buf][(it * 256 + (wid << 6)) * 8]);
    }
  };
  auto comp = [&](int buf) {
#pragma unroll
    for (int ks = 0; ks < 2; ++ks) {
      const int so = (((ks * 4 + l4) ^ swz) << 3);
      short8 av[4], bv[4];
#pragma unroll
      for (int i = 0; i < 4; ++i)
        av[i] = *(const short8*)&As[buf][(wr + i * 16 + l15) * 64 + so];
#pragma unroll
      for (int j = 0; j < 4; ++j)
        bv[j] = *(const short8*)&Bs[buf][(wc + j * 16 + l15) * 64 + so];
#pragma unroll
      for (int i = 0; i < 4; ++i)
#pragma unroll
        for (int j = 0; j < 4; ++j)
          acc[i][j] = __builtin_amdgcn_mfma_f32_16x16x32_bf16(av[i], bv[j],
                                                              acc[i][j], 0, 0, 0);
    }
  };

  stage(0, kbase);
  __syncthreads();
  for (int k0 = kbase; k0 < kbase + 1024; k0 += 128) {
    stage(1, k0 + 64);
    comp(0);
    __syncthreads();
    if (k0 + 128 < kbase + 1024) stage(0, k0 + 128);
    comp(1);
    __syncthreads();
  }

  float* Pk = P + (size_t)kidx * BSZ * NPAD;
#pragma unroll
  for (int j = 0; j < 4; ++j) {
    const int col = bn0 + wc + j * 16 + l15;
#pragma unroll
    for (int i = 0; i < 4; ++i) {
#pragma unroll
      for (int r = 0; r < 4; ++r) {
        const int row = bm0 + wr + i * 16 + l4 * 4 + r;
        Pk[(size_t)row * NPAD + col] = acc[i][j][r];
      }
    }
  }
}

// ------ combine: out = -0.1*sqrt(max(f2 + c2 - 2*(P0+P1), 0)) --------------
__global__ __launch_bounds__(256) void combine(const float* __restrict__ P,
                                               const float* __restrict__ f2,
                                               const float* __restrict__ c2,
                                               float* __restrict__ out) {
  const int row = blockIdx.x;
  const int c = threadIdx.x * 4;
  if (c >= NCLS) return;
  const float4 p0 = *(const float4*)&P[(size_t)row * NPAD + c];
  const float4 p1 = *(const float4*)&P[(size_t)(BSZ + row) * NPAD + c];
  const float4 cv = *(const float4*)&c2[c];
  const float fv = f2[row];
  float4 o;
  o.x = -0.1f * sqrtf(fmaxf(fv + cv.x - 2.f * (p0.x + p1.x), 0.f));
  o.y = -0.1f * sqrtf(fmaxf(fv + cv.y - 2.f * (p0.y + p1.y), 0.f));
  o.z = -0.1f * sqrtf(fmaxf(fv + cv.z - 2.f * (p0.z + p1.z), 0.f));
  o.w = -0.1f * sqrtf(fmaxf(fv + cv.w - 2.f * (p0.w + p1.w), 0.f));
  *(float4*)&out[(size_t)row * NCLS + c] = o;
}

extern "C" void kernel_launch(void* const* d_in, const int* in_sizes, int n_in,
                              void* d_out, int out_size, void* d_ws, size_t ws_size,
                              hipStream_t stream) {
  const float* x    = (const float*)d_in[0];
  const float* x90  = (const float*)d_in[1];
  const float* x180 = (const float*)d_in[2];
  const float* x270 = (const float*)d_in[3];
  const float* W_f  = (const float*)d_in[4];
  const float* b_f  = (const float*)d_in[5];
  const float* W_r  = (const float*)d_in[6];
  const float* b_r  = (const float*)d_in[7];
  const float* cen  = (const float*)d_in[8];
  float* out = (float*)d_out;

  // workspace layout (bf16 as u16)
  u16* Xb = (u16*)d_ws;                         // [4][4096][1024]
  u16* Wb = Xb + 4ull * BSZ * INF;              // [2][512][1024]
  u16* Cb = Wb + 2ull * FEAT * INF;             // [1024][2048]
  u16* Fb = Cb + (size_t)NPAD * DTOT;           // [4096][2048]
  float* f2 = (float*)(Fb + (size_t)BSZ * DTOT);// [4096]
  float* c2 = f2 + BSZ;                         // [1024]
  float* f2p = c2 + NPAD;                       // [32][4096]
  float* P   = f2p + 32ull * BSZ;               // [2][4096][1024] fp32

  const int n8x = BSZ * INF / 8;   // 524288
  const int n8w = FEAT * INF / 8;  // 65536
  cvt_bf16_x4<<<dim3((n8x + 255) / 256, 4), 256, 0, stream>>>(x, x90, x180, x270,
                                                              Xb, n8x);
  cvt_bf16<<<(n8w + 255) / 256, 256, 0, stream>>>(W_f, Wb, n8w);
  cvt_bf16<<<(n8w + 255) / 256, 256, 0, stream>>>(W_r, Wb + (size_t)FEAT * INF, n8w);
  cvt_centers<<<NPAD, 256, 0, stream>>>(cen, Cb, c2);

  feat_gemm<<<512, 256, 0, stream>>>(Xb, Wb, b_f, b_r, Fb, f2p);
  reduce_f2<<<BSZ / 256, 256, 0, stream>>>(f2p, f2);
  dist_gemm_sk<<<512, 256, 0, stream>>>(Fb, Cb, P);
  combine<<<BSZ, 256, 0, stream>>>(P, f2, c2, out);
}